// Round 1
// baseline (160.525 us; speedup 1.0000x reference)
//
#include <hip/hip_runtime.h>
#include <float.h>

#define N 512

// ws layout (floats):
// [0,512)                x
// [512,1024)             mask (int view)
// [1024,1025)            changed flag (int view)
// [2048, 2048+64*512)    partial  (64 blocks x 512)
// [34816, 34816+512*512) S

__global__ __launch_bounds__(512) void k_init(const float* __restrict__ x0,
                                              float* __restrict__ x,
                                              int* __restrict__ mask,
                                              int* __restrict__ changed) {
    int k = threadIdx.x;
    float v = fmaxf(x0[k], 0.0f);
    x[k] = v;
    mask[k] = (v > 0.0f) ? 1 : 0;
    if (k == 0) *changed = 1;
}

// Block a: masked softmax of logits row a (into LDS), then
// S[a,k] = sum_b Qi[a,b] * T[a,b,k].  Early-exit when mask unchanged.
__global__ __launch_bounds__(128) void k_qis(const float* __restrict__ logits,
                                             const float* __restrict__ T,
                                             const int* __restrict__ tgt,
                                             const int* __restrict__ mask,
                                             const int* __restrict__ changed,
                                             float* __restrict__ S) {
    if (*changed == 0) return;

    const int a = blockIdx.x;
    const int t = threadIdx.x;
    const int target = tgt[0];

    __shared__ float qs[N];
    __shared__ float redf[128];
    __shared__ int   redi[128];

    // ---- phase 1: masked row softmax ----
    float lg[4];
    int   p2[4];
    float mx = -FLT_MAX;
    int   cnt = 0;
#pragma unroll
    for (int u = 0; u < 4; ++u) {
        int b = t + u * 128;
        int p = (mask[b] != 0) && (b != target);
        float l = logits[(size_t)a * N + b];
        lg[u] = l;
        p2[u] = p;
        if (p) { mx = fmaxf(mx, l); cnt += 1; }
    }
    redf[t] = mx;
    redi[t] = cnt;
    __syncthreads();
    for (int s = 64; s > 0; s >>= 1) {
        if (t < s) {
            redf[t] = fmaxf(redf[t], redf[t + s]);
            redi[t] += redi[t + s];
        }
        __syncthreads();
    }
    mx  = redf[0];
    cnt = redi[0];
    const int  p1a    = mask[a];
    const bool rowzero = (p1a == 0) || (cnt == 0);

    const int k0 = t * 4;
    float4 acc = make_float4(0.0f, 0.0f, 0.0f, 0.0f);

    if (!rowzero) {
        float ev[4];
        float sum = 0.0f;
#pragma unroll
        for (int u = 0; u < 4; ++u) {
            float e = p2[u] ? expf(lg[u] - mx) : 0.0f;
            ev[u] = e;
            sum += e;
        }
        __syncthreads();           // everyone done reading redf[0]
        redf[t] = sum;
        __syncthreads();
        for (int s = 64; s > 0; s >>= 1) {
            if (t < s) redf[t] += redf[t + s];
            __syncthreads();
        }
        const float inv = 1.0f / redf[0];
#pragma unroll
        for (int u = 0; u < 4; ++u) qs[t + u * 128] = ev[u] * inv;
        __syncthreads();

        // ---- phase 2: S[a, k0..k0+3] = sum_b qs[b] * T[a,b,k] ----
        const float* Trow = T + (size_t)a * N * N + k0;
        for (int b = 0; b < N; b += 8) {
#pragma unroll
            for (int u = 0; u < 8; ++u) {
                float qb = qs[b + u];
                const float4 tv =
                    *reinterpret_cast<const float4*>(Trow + (size_t)(b + u) * N);
                acc.x = fmaf(qb, tv.x, acc.x);
                acc.y = fmaf(qb, tv.y, acc.y);
                acc.z = fmaf(qb, tv.z, acc.z);
                acc.w = fmaf(qb, tv.w, acc.w);
            }
        }
    }
    *reinterpret_cast<float4*>(S + (size_t)a * N + k0) = acc;
}

// Block bp handles 8 rows of S: partial[bp][k] = sum_{a in chunk} x[a]*S[a,k]
__global__ __launch_bounds__(512) void k_part(const float* __restrict__ x,
                                              const float* __restrict__ S,
                                              float* __restrict__ partial) {
    const int k  = threadIdx.x;
    const int bp = blockIdx.x;
    __shared__ float xs[8];
    if (k < 8) xs[k] = x[bp * 8 + k];
    __syncthreads();
    float acc = 0.0f;
#pragma unroll
    for (int i = 0; i < 8; ++i)
        acc = fmaf(xs[i], S[(size_t)(bp * 8 + i) * N + k], acc);
    partial[(size_t)bp * N + k] = acc;
}

// Reduce partials, relu-update x, recompute mask, set changed flag.
__global__ __launch_bounds__(512) void k_fin(float* __restrict__ x,
                                             const float* __restrict__ partial,
                                             int* __restrict__ mask,
                                             int* __restrict__ changed,
                                             float* __restrict__ out,
                                             int last) {
    const int k = threadIdx.x;
    float off = 0.0f;
    for (int bp = 0; bp < 64; ++bp)
        off += partial[(size_t)bp * N + k];
    float xn = fmaxf(x[k] + off, 0.0f);
    x[k] = xn;
    const int p1  = (xn > 0.0f) ? 1 : 0;
    const int old = mask[k];
    mask[k] = p1;
    __shared__ int diff;
    if (k == 0) diff = 0;
    __syncthreads();
    if (p1 != old) atomicOr(&diff, 1);
    __syncthreads();
    if (k == 0) *changed = diff;
    if (last) out[k] = xn;
}

extern "C" void kernel_launch(void* const* d_in, const int* in_sizes, int n_in,
                              void* d_out, int out_size, void* d_ws, size_t ws_size,
                              hipStream_t stream) {
    const float* x0     = (const float*)d_in[0];
    const float* logits = (const float*)d_in[1];
    const float* T      = (const float*)d_in[2];
    const int*   tgt    = (const int*)d_in[3];

    float* ws      = (float*)d_ws;
    float* x       = ws;
    int*   mask    = (int*)(ws + 512);
    int*   changed = (int*)(ws + 1024);
    float* partial = ws + 2048;
    float* S       = ws + 2048 + 64 * 512;
    float* out     = (float*)d_out;

    k_init<<<1, 512, 0, stream>>>(x0, x, mask, changed);
    for (int w = 0; w < 8; ++w) {
        k_qis<<<512, 128, 0, stream>>>(logits, T, tgt, mask, changed, S);
        k_part<<<64, 512, 0, stream>>>(x, S, partial);
        k_fin<<<1, 512, 0, stream>>>(x, partial, mask, changed, out, (w == 7) ? 1 : 0);
    }
}

// Round 2
// 159.884 us; speedup vs baseline: 1.0040x; 1.0040x over previous
//
#include <hip/hip_runtime.h>
#include <float.h>

#define NN 512

// ws layout:
// [0, 512*512) floats : S
// then 2 ints          : barrier {count, gen}

__device__ __forceinline__ void gbar(int* cnt, int* gen, int nb) {
    __syncthreads();
    if (threadIdx.x == 0) {
        __threadfence();
        int mygen = __hip_atomic_load(gen, __ATOMIC_SEQ_CST, __HIP_MEMORY_SCOPE_AGENT);
        int old   = __hip_atomic_fetch_add(cnt, 1, __ATOMIC_SEQ_CST, __HIP_MEMORY_SCOPE_AGENT);
        if (old == nb - 1) {
            __hip_atomic_store(cnt, 0, __ATOMIC_SEQ_CST, __HIP_MEMORY_SCOPE_AGENT);
            __hip_atomic_fetch_add(gen, 1, __ATOMIC_SEQ_CST, __HIP_MEMORY_SCOPE_AGENT);
        } else {
            while (__hip_atomic_load(gen, __ATOMIC_SEQ_CST, __HIP_MEMORY_SCOPE_AGENT) == mygen)
                __builtin_amdgcn_s_sleep(8);
        }
        __threadfence();
    }
    __syncthreads();
}

// Block a: mask from x0, masked softmax of logits row a, then
// S[a,k] = sum_b Qi[a,b] * T[a,b,k].  One full streaming pass over T.
__global__ __launch_bounds__(256) void k_qis(const float* __restrict__ x0,
                                             const float* __restrict__ logits,
                                             const float* __restrict__ T,
                                             const int* __restrict__ tgt,
                                             float* __restrict__ S,
                                             int* __restrict__ bar) {
    const int a = blockIdx.x;
    const int t = threadIdx.x;
    if (a == 0 && t == 0) bar[0] = 0;   // zero barrier count for k_tail
    const int target = tgt[0];

    __shared__ float redf[256];
    __shared__ int   redi[256];
    __shared__ float qs[NN];

    const float l0 = logits[(size_t)a * NN + t];
    const float l1 = logits[(size_t)a * NN + t + 256];
    const int p0 = (x0[t]       > 0.0f && t       != target) ? 1 : 0;
    const int p1 = (x0[t + 256] > 0.0f && t + 256 != target) ? 1 : 0;

    float mx = -FLT_MAX;
    if (p0) mx = l0;
    if (p1) mx = fmaxf(mx, l1);
    redf[t] = mx;
    redi[t] = p0 + p1;
    __syncthreads();
    for (int s = 128; s > 0; s >>= 1) {
        if (t < s) { redf[t] = fmaxf(redf[t], redf[t + s]); redi[t] += redi[t + s]; }
        __syncthreads();
    }
    mx = redf[0];
    const int  cnt     = redi[0];
    const bool rowzero = (!(x0[a] > 0.0f)) || (cnt == 0);   // block-uniform

    float2 acc = make_float2(0.0f, 0.0f);
    const int k0 = 2 * t;
    if (!rowzero) {
        const float e0 = p0 ? expf(l0 - mx) : 0.0f;
        const float e1 = p1 ? expf(l1 - mx) : 0.0f;
        __syncthreads();
        redf[t] = e0 + e1;
        __syncthreads();
        for (int s = 128; s > 0; s >>= 1) {
            if (t < s) redf[t] += redf[t + s];
            __syncthreads();
        }
        const float inv = 1.0f / redf[0];
        qs[t] = e0 * inv;
        qs[t + 256] = e1 * inv;
        __syncthreads();

        const float* Tp = T + (size_t)a * NN * NN + k0;
        for (int b = 0; b < NN; b += 8) {
#pragma unroll
            for (int u = 0; u < 8; ++u) {
                const float  qb = qs[b + u];
                const float2 tv = *reinterpret_cast<const float2*>(Tp + (size_t)(b + u) * NN);
                acc.x = fmaf(qb, tv.x, acc.x);
                acc.y = fmaf(qb, tv.y, acc.y);
            }
        }
    }
    *reinterpret_cast<float2*>(S + (size_t)a * NN + k0) = acc;
}

// All 8 waves in one kernel. Each of 64 blocks redundantly computes the full
// matvec + update (S is L2-resident) -> no inter-block traffic in fast path.
// If the mask ever changes, all blocks agree and recompute S (grid barriers).
__global__ __launch_bounds__(512) void k_tail(const float* __restrict__ x0,
                                              const float* __restrict__ logits,
                                              const float* __restrict__ T,
                                              const int* __restrict__ tgt,
                                              float* __restrict__ S,
                                              int* __restrict__ bar,
                                              float* __restrict__ out) {
    const int bp = blockIdx.x;
    const int t  = threadIdx.x;
    const int target = tgt[0];

    __shared__ float         xs[NN];
    __shared__ unsigned char msk[NN];
    __shared__ float4        red4[4][128];
    __shared__ float         redf[NN];
    __shared__ int           redi[NN];
    __shared__ float         qs[NN];
    __shared__ int           chg;

    {
        const float xv = fmaxf(x0[t], 0.0f);
        xs[t]  = xv;
        msk[t] = (xv > 0.0f) ? 1 : 0;
    }
    __syncthreads();

    const int g = t >> 7;    // row subgroup 0..3
    const int c = t & 127;   // column-quad index

    for (int w = 0; w < 8; ++w) {
        if (t == 0) chg = 0;
        // ---- matvec: off[k] = sum_a xs[a] * S[a][k] ----
        float4 o = make_float4(0.0f, 0.0f, 0.0f, 0.0f);
        const float* Sp = S + 4 * c;
#pragma unroll 4
        for (int a = g; a < NN; a += 4) {
            const float  xa = xs[a];
            const float4 sv = *reinterpret_cast<const float4*>(Sp + (size_t)a * NN);
            o.x = fmaf(xa, sv.x, o.x);
            o.y = fmaf(xa, sv.y, o.y);
            o.z = fmaf(xa, sv.z, o.z);
            o.w = fmaf(xa, sv.w, o.w);
        }
        red4[g][c] = o;
        __syncthreads();

        // ---- update x, mask, changed (threads 0..127, 4 k's each) ----
        if (t < 128) {
            const float4 r0 = red4[0][t], r1 = red4[1][t], r2 = red4[2][t], r3 = red4[3][t];
            float off[4];
            off[0] = ((r0.x + r1.x) + r2.x) + r3.x;
            off[1] = ((r0.y + r1.y) + r2.y) + r3.y;
            off[2] = ((r0.z + r1.z) + r2.z) + r3.z;
            off[3] = ((r0.w + r1.w) + r2.w) + r3.w;
            int d = 0;
#pragma unroll
            for (int j = 0; j < 4; ++j) {
                const int k = 4 * t + j;
                const float xn = fmaxf(xs[k] + off[j], 0.0f);
                const unsigned char nm = (xn > 0.0f) ? 1 : 0;
                if (nm != msk[k]) d = 1;
                xs[k]  = xn;
                msk[k] = nm;
            }
            if (d) atomicOr(&chg, 1);
        }
        __syncthreads();
        const bool changed = (chg != 0);   // identical across blocks
        __syncthreads();                   // separate read from next wave's chg=0

        if (w < 7 && changed) {
            // ---- slow path (mask flipped): recompute S rows bp*8..bp*8+7 ----
            gbar(&bar[0], &bar[1], 64);    // all blocks done reading old S
            for (int r = 0; r < 8; ++r) {
                const int a = bp * 8 + r;
                const float l = logits[(size_t)a * NN + t];
                const int   p = (msk[t] && (t != target)) ? 1 : 0;
                redf[t] = p ? l : -FLT_MAX;
                redi[t] = p;
                __syncthreads();
                for (int s = 256; s > 0; s >>= 1) {
                    if (t < s) { redf[t] = fmaxf(redf[t], redf[t + s]); redi[t] += redi[t + s]; }
                    __syncthreads();
                }
                const float mx  = redf[0];
                const int   cnt = redi[0];
                __syncthreads();
                const float e = p ? expf(l - mx) : 0.0f;
                redf[t] = e;
                __syncthreads();
                for (int s = 256; s > 0; s >>= 1) {
                    if (t < s) redf[t] += redf[t + s];
                    __syncthreads();
                }
                const float inv     = 1.0f / redf[0];
                const bool  rowzero = (!msk[a]) || (cnt == 0);   // block-uniform
                qs[t] = rowzero ? 0.0f : e * inv;
                __syncthreads();
                float accr = 0.0f;
                if (!rowzero) {
                    const float* Tp = T + (size_t)a * NN * NN + t;
                    for (int b = 0; b < NN; b += 4) {
#pragma unroll
                        for (int u = 0; u < 4; ++u)
                            accr = fmaf(qs[b + u], Tp[(size_t)(b + u) * NN], accr);
                    }
                }
                S[(size_t)a * NN + t] = accr;
                __syncthreads();
            }
            gbar(&bar[0], &bar[1], 64);    // new S visible everywhere
        }
    }

    if (bp == 0) out[t] = xs[t];
}

extern "C" void kernel_launch(void* const* d_in, const int* in_sizes, int n_in,
                              void* d_out, int out_size, void* d_ws, size_t ws_size,
                              hipStream_t stream) {
    const float* x0     = (const float*)d_in[0];
    const float* logits = (const float*)d_in[1];
    const float* T      = (const float*)d_in[2];
    const int*   tgt    = (const int*)d_in[3];

    float* S   = (float*)d_ws;
    int*   bar = (int*)((char*)d_ws + (size_t)NN * NN * sizeof(float));
    float* out = (float*)d_out;

    k_qis<<<512, 256, 0, stream>>>(x0, logits, T, tgt, S, bar);
    k_tail<<<64, 512, 0, stream>>>(x0, logits, T, tgt, S, bar, out);
}

// Round 5
// 134.118 us; speedup vs baseline: 1.1969x; 1.1921x over previous
//
#include <hip/hip_runtime.h>
#include <float.h>

#define NN 512
#define TB 32   // tail blocks; each owns NN/TB = 16 rows of S

typedef float f32x4 __attribute__((ext_vector_type(4)));

// ws layout (floats):
// [0, 512*512)                       : S
// [512*512, 512*512 + 2*TB*512)      : partial, double-buffered by wave parity
// then 2 ints                        : barrier {count, gen}

__device__ __forceinline__ void gbar(int* cnt, int* gen, int nb) {
    __syncthreads();
    if (threadIdx.x == 0) {
        __threadfence();
        int mygen = __hip_atomic_load(gen, __ATOMIC_SEQ_CST, __HIP_MEMORY_SCOPE_AGENT);
        int old   = __hip_atomic_fetch_add(cnt, 1, __ATOMIC_SEQ_CST, __HIP_MEMORY_SCOPE_AGENT);
        if (old == nb - 1) {
            __hip_atomic_store(cnt, 0, __ATOMIC_SEQ_CST, __HIP_MEMORY_SCOPE_AGENT);
            __hip_atomic_fetch_add(gen, 1, __ATOMIC_SEQ_CST, __HIP_MEMORY_SCOPE_AGENT);
        } else {
            while (__hip_atomic_load(gen, __ATOMIC_SEQ_CST, __HIP_MEMORY_SCOPE_AGENT) == mygen)
                __builtin_amdgcn_s_sleep(8);
        }
        __threadfence();
    }
    __syncthreads();
}

// Block a (512 blocks x 512 thr): mask from x0, masked softmax of logits row a,
// S[a,k] = sum_b Qi[a,b]*T[a,b,k]. One streaming float4 NT pass over T[a,:,:].
__global__ __launch_bounds__(512) void k_qis(const float* __restrict__ x0,
                                             const float* __restrict__ logits,
                                             const float* __restrict__ T,
                                             const int* __restrict__ tgt,
                                             float* __restrict__ S,
                                             int* __restrict__ bar) {
    const int a = blockIdx.x;
    const int t = threadIdx.x;
    if (a == 0 && t == 0) bar[0] = 0;   // barrier count ready for k_tail
    const int target = tgt[0];

    __shared__ float  redf[NN];
    __shared__ int    redi[NN];
    __shared__ float  qs[NN];
    __shared__ f32x4  red4[4][128];

    const float l = logits[(size_t)a * NN + t];
    const int   p = (x0[t] > 0.0f && t != target) ? 1 : 0;
    redf[t] = p ? l : -FLT_MAX;
    redi[t] = p;
    __syncthreads();
    for (int s = 256; s > 0; s >>= 1) {
        if (t < s) { redf[t] = fmaxf(redf[t], redf[t + s]); redi[t] += redi[t + s]; }
        __syncthreads();
    }
    const float mx  = redf[0];
    const int   cnt = redi[0];
    __syncthreads();
    const float e = p ? expf(l - mx) : 0.0f;
    redf[t] = e;
    __syncthreads();
    for (int s = 256; s > 0; s >>= 1) {
        if (t < s) redf[t] += redf[t + s];
        __syncthreads();
    }
    const float inv = 1.0f / redf[0];
    qs[t] = e * inv;
    __syncthreads();

    const bool rowzero = (!(x0[a] > 0.0f)) || (cnt == 0);   // block-uniform
    const int  c = t & 127;   // k-quad
    const int  g = t >> 7;    // b subgroup
    f32x4 acc = {0.0f, 0.0f, 0.0f, 0.0f};
    if (!rowzero) {
        const float* Tp = T + (size_t)a * NN * NN + 4 * c;
#pragma unroll 8
        for (int b = g; b < NN; b += 4) {
            const float qb = qs[b];
            const f32x4 tv = __builtin_nontemporal_load(
                reinterpret_cast<const f32x4*>(Tp + (size_t)b * NN));
            acc.x = fmaf(qb, tv.x, acc.x);
            acc.y = fmaf(qb, tv.y, acc.y);
            acc.z = fmaf(qb, tv.z, acc.z);
            acc.w = fmaf(qb, tv.w, acc.w);
        }
    }
    red4[g][c] = acc;
    __syncthreads();
    if (t < 128) {
        const f32x4 r0 = red4[0][t], r1 = red4[1][t], r2 = red4[2][t], r3 = red4[3][t];
        f32x4 o;
        o.x = (r0.x + r1.x) + (r2.x + r3.x);
        o.y = (r0.y + r1.y) + (r2.y + r3.y);
        o.z = (r0.z + r1.z) + (r2.z + r3.z);
        o.w = (r0.w + r1.w) + (r2.w + r3.w);
        *reinterpret_cast<f32x4*>(S + (size_t)a * NN + 4 * t) = o;
    }
}

// TB blocks x 512 thr, all 8 waves. Cooperative matvec, partial double-buffered
// by wave parity (fixes write-after-read race across the single grid barrier):
// wave w writes partial[w&1]; all blocks pass gbar(w) before reading it, and
// must pass gbar(w+1) before anyone can rewrite buffer w&1 (at wave w+2).
// Fixed summation order -> bit-identical x/mask in every block -> uniform
// slow-path decision.
__global__ __launch_bounds__(512) void k_tail(const float* __restrict__ x0,
                                              const float* __restrict__ logits,
                                              const float* __restrict__ T,
                                              const int* __restrict__ tgt,
                                              float* __restrict__ S,
                                              float* __restrict__ partial,
                                              int* __restrict__ bar,
                                              float* __restrict__ out) {
    const int bp = blockIdx.x;
    const int t  = threadIdx.x;
    const int target = tgt[0];

    __shared__ float         xs[NN];
    __shared__ unsigned char msk[NN];
    __shared__ int           chg;
    __shared__ float         redf[NN];
    __shared__ int           redi[NN];
    __shared__ float         qs[NN];

    {
        const float xv = fmaxf(x0[t], 0.0f);
        xs[t]  = xv;
        msk[t] = (xv > 0.0f) ? 1 : 0;
    }
    __syncthreads();

    const int R  = NN / TB;      // rows per block
    const int r0 = bp * R;
    for (int w = 0; w < 8; ++w) {
        float* pbuf = partial + (size_t)(w & 1) * TB * NN;
        // ---- pbuf[bp][t] = sum_{i<R} xs[r0+i] * S[r0+i][t] ----
        float pa = 0.0f;
#pragma unroll
        for (int i = 0; i < R; ++i)
            pa = fmaf(xs[r0 + i], S[(size_t)(r0 + i) * NN + t], pa);
        pbuf[(size_t)bp * NN + t] = pa;

        gbar(&bar[0], &bar[1], TB);      // partials for wave w visible

        if (t == 0) chg = 0;
        float off = 0.0f;
#pragma unroll 8
        for (int b = 0; b < TB; ++b)
            off += pbuf[(size_t)b * NN + t];
        __syncthreads();                 // chg=0 visible before atomicOr
        const float xn = fmaxf(xs[t] + off, 0.0f);
        const unsigned char nm = (xn > 0.0f) ? 1 : 0;
        if (nm != msk[t]) atomicOr(&chg, 1);
        xs[t]  = xn;
        msk[t] = nm;
        __syncthreads();
        const bool changed = (chg != 0); // identical across blocks

        if (w < 7 && changed) {
            // ---- slow path: recompute S rows r0..r0+R-1 under new mask ----
            gbar(&bar[0], &bar[1], TB);  // all wave-w S reads done
            for (int r = 0; r < R; ++r) {
                const int a = r0 + r;
                const float l = logits[(size_t)a * NN + t];
                const int   p = (msk[t] && (t != target)) ? 1 : 0;
                redf[t] = p ? l : -FLT_MAX;
                redi[t] = p;
                __syncthreads();
                for (int s = 256; s > 0; s >>= 1) {
                    if (t < s) { redf[t] = fmaxf(redf[t], redf[t + s]); redi[t] += redi[t + s]; }
                    __syncthreads();
                }
                const float mx  = redf[0];
                const int   cnt = redi[0];
                __syncthreads();
                const float e = p ? expf(l - mx) : 0.0f;
                redf[t] = e;
                __syncthreads();
                for (int s = 256; s > 0; s >>= 1) {
                    if (t < s) redf[t] += redf[t + s];
                    __syncthreads();
                }
                const float inv     = 1.0f / redf[0];
                const bool  rowzero = (!msk[a]) || (cnt == 0);
                qs[t] = rowzero ? 0.0f : e * inv;
                __syncthreads();
                float accr = 0.0f;
                if (!rowzero) {
                    const float* Tp = T + (size_t)a * NN * NN + t;
                    for (int b = 0; b < NN; b += 4) {
#pragma unroll
                        for (int u = 0; u < 4; ++u)
                            accr = fmaf(qs[b + u], Tp[(size_t)(b + u) * NN], accr);
                    }
                }
                S[(size_t)a * NN + t] = accr;
                __syncthreads();
            }
            gbar(&bar[0], &bar[1], TB);  // new S visible before next wave
        }
    }

    if (bp == 0) out[t] = xs[t];
}

extern "C" void kernel_launch(void* const* d_in, const int* in_sizes, int n_in,
                              void* d_out, int out_size, void* d_ws, size_t ws_size,
                              hipStream_t stream) {
    const float* x0     = (const float*)d_in[0];
    const float* logits = (const float*)d_in[1];
    const float* T      = (const float*)d_in[2];
    const int*   tgt    = (const int*)d_in[3];

    float* S       = (float*)d_ws;
    float* partial = S + (size_t)NN * NN;
    int*   bar     = (int*)(partial + 2 * TB * NN);
    float* out     = (float*)d_out;

    k_qis<<<512, 512, 0, stream>>>(x0, logits, T, tgt, S, bar);
    k_tail<<<TB, 512, 0, stream>>>(x0, logits, T, tgt, S, partial, bar, out);
}